// Round 2
// baseline (406.707 us; speedup 1.0000x reference)
//
#include <hip/hip_runtime.h>
#include <hip/hip_bf16.h>

// DCell forward, MI355X (gfx950). All inputs/outputs are fp32 (per reference).
// One block per term => BatchNorm (batch axis) is block-local; stages are
// sequenced by stream-ordered launches.
// Linear bias b{3,2,1,0} provably cancels inside BatchNorm (z - mean), never read.
// ws layout (fp32 elements): [h3 | h2 | h1 | z0] ~= 55 MB.

#define DEV static __device__ __forceinline__

constexpr int B_  = 256, G_ = 64, D_ = 20;
constexpr int T3_ = 2048, T2_ = 512, T1_ = 128;
constexpr float EPS_ = 1e-5f;

constexpr int IN3 = G_;            // 64
constexpr int INM = 4 * D_ + G_;   // 144

constexpr size_t OFF_H3 = 0;
constexpr size_t N_H3 = (size_t)B_ * T3_ * D_;   // 10,485,760
constexpr size_t OFF_H2 = OFF_H3 + N_H3;
constexpr size_t N_H2 = (size_t)B_ * T2_ * D_;   //  2,621,440
constexpr size_t OFF_H1 = OFF_H2 + N_H2;
constexpr size_t N_H1 = (size_t)B_ * T1_ * D_;   //    655,360
constexpr size_t OFF_Z0 = OFF_H1 + N_H1;

DEV float fast_tanh(float x) {
    // tanh(x) = 1 - 2/(exp(2x)+1); exact at +-inf, rel err ~1e-6.
    float e = __expf(2.0f * x);
    return fmaf(-2.0f, __builtin_amdgcn_rcpf(e + 1.0f), 1.0f);
}

// ---- BN (batch-local within block) + tanh + store ---------------------------
DEV void bn_tanh_store(float (&acc)[D_], const float* gp, const float* bep,
                       float* dst, int tid) {
    __shared__ float sred[4][D_], qred[4][D_], Avec[D_], Cvec[D_];
    const int lane = tid & 63, wave = tid >> 6;
    float s[D_], q[D_];
#pragma unroll
    for (int o = 0; o < D_; ++o) { s[o] = acc[o]; q[o] = acc[o] * acc[o]; }
#pragma unroll
    for (int off = 32; off; off >>= 1) {
#pragma unroll
        for (int o = 0; o < D_; ++o) {
            s[o] += __shfl_xor(s[o], off, 64);
            q[o] += __shfl_xor(q[o], off, 64);
        }
    }
    if (lane == 0) {
#pragma unroll
        for (int o = 0; o < D_; ++o) { sred[wave][o] = s[o]; qred[wave][o] = q[o]; }
    }
    __syncthreads();
    if (tid < D_) {
        float S = sred[0][tid] + sred[1][tid] + sred[2][tid] + sred[3][tid];
        float Q = qred[0][tid] + qred[1][tid] + qred[2][tid] + qred[3][tid];
        float mu  = S * (1.0f / B_);
        float var = fmaxf(Q * (1.0f / B_) - mu * mu, 0.0f);
        float rstd = rsqrtf(var + EPS_);
        float A = rstd * gp[tid];
        Avec[tid] = A;
        Cvec[tid] = bep[tid] - mu * A;
    }
    __syncthreads();
    float h[D_];
#pragma unroll
    for (int o = 0; o < D_; ++o) h[o] = fast_tanh(fmaf(acc[o], Avec[o], Cvec[o]));
    float4* d4 = (float4*)dst;
#pragma unroll
    for (int v = 0; v < D_ / 4; ++v)
        d4[v] = make_float4(h[4 * v], h[4 * v + 1], h[4 * v + 2], h[4 * v + 3]);
}

// ---- stratum 3 (leaves): x = genes (64 fp32) --------------------------------
__global__ __launch_bounds__(256) void k_stage3(const float* __restrict__ genes,
                                                const float* __restrict__ W,
                                                const float* __restrict__ g,
                                                const float* __restrict__ be,
                                                float* __restrict__ hout) {
    const int t = blockIdx.x, b = threadIdx.x;
    const float4* gp = (const float4*)(genes + ((size_t)b * T3_ + t) * G_);
    const float* Wt = W + (size_t)t * (IN3 * D_);
    float acc[D_] = {};
#pragma unroll
    for (int v = 0; v < G_ / 4; ++v) {
        float4 f = gp[v];
        float x4[4] = {f.x, f.y, f.z, f.w};
#pragma unroll
        for (int j = 0; j < 4; ++j) {
            const float* w = Wt + (v * 4 + j) * D_;
#pragma unroll
            for (int o = 0; o < D_; ++o) acc[o] = fmaf(x4[j], w[o], acc[o]);
        }
    }
    bn_tanh_store(acc, g + (size_t)t * D_, be + (size_t)t * D_,
                  hout + ((size_t)b * T3_ + t) * D_, b);
}

// ---- strata 2/1: x = [4 children (80 fp32) | genes (64 fp32)] ---------------
template <int T>
__global__ __launch_bounds__(256) void k_stage_mid(const float* __restrict__ hsrc,
                                                   const float* __restrict__ genes,
                                                   const float* __restrict__ W,
                                                   const float* __restrict__ g,
                                                   const float* __restrict__ be,
                                                   float* __restrict__ hout) {
    const int t = blockIdx.x, b = threadIdx.x;
    const float4* hp = (const float4*)(hsrc + ((size_t)b * (4 * T) + 4 * t) * D_);
    const float* Wt = W + (size_t)t * (INM * D_);
    float acc[D_] = {};
#pragma unroll
    for (int v = 0; v < (4 * D_) / 4; ++v) {   // 80 child features
        float4 f = hp[v];
        float x4[4] = {f.x, f.y, f.z, f.w};
#pragma unroll
        for (int j = 0; j < 4; ++j) {
            const float* w = Wt + (v * 4 + j) * D_;
#pragma unroll
            for (int o = 0; o < D_; ++o) acc[o] = fmaf(x4[j], w[o], acc[o]);
        }
    }
    const float4* gp = (const float4*)(genes + ((size_t)b * T + t) * G_);
#pragma unroll
    for (int v = 0; v < G_ / 4; ++v) {
        float4 f = gp[v];
        float x4[4] = {f.x, f.y, f.z, f.w};
#pragma unroll
        for (int j = 0; j < 4; ++j) {
            const float* w = Wt + (4 * D_ + v * 4 + j) * D_;
#pragma unroll
            for (int o = 0; o < D_; ++o) acc[o] = fmaf(x4[j], w[o], acc[o]);
        }
    }
    bn_tanh_store(acc, g + (size_t)t * D_, be + (size_t)t * D_,
                  hout + ((size_t)b * T + t) * D_, b);
}

// ---- root GEMV part: one block per batch row, K-strided ---------------------
__global__ __launch_bounds__(256) void k_stage0a(const float* __restrict__ h1,
                                                 const float* __restrict__ genes0,
                                                 const float* __restrict__ W0,
                                                 float* __restrict__ z0) {
    const int b = blockIdx.x, tid = threadIdx.x;
    const float* x = h1 + (size_t)b * (T1_ * D_);
    float acc[D_] = {};
#pragma unroll
    for (int jj = 0; jj < (T1_ * D_) / 256; ++jj) {   // 10 iters, k = tid + 256*jj
        int k = tid + jj * 256;
        float xk = x[k];
        const float4* w = (const float4*)(W0 + (size_t)k * D_);
#pragma unroll
        for (int v = 0; v < D_ / 4; ++v) {
            float4 f = w[v];
            acc[4 * v + 0] = fmaf(xk, f.x, acc[4 * v + 0]);
            acc[4 * v + 1] = fmaf(xk, f.y, acc[4 * v + 1]);
            acc[4 * v + 2] = fmaf(xk, f.z, acc[4 * v + 2]);
            acc[4 * v + 3] = fmaf(xk, f.w, acc[4 * v + 3]);
        }
    }
    if (tid < G_) {
        float xk = genes0[(size_t)b * G_ + tid];
        const float4* w = (const float4*)(W0 + (size_t)(T1_ * D_ + tid) * D_);
#pragma unroll
        for (int v = 0; v < D_ / 4; ++v) {
            float4 f = w[v];
            acc[4 * v + 0] = fmaf(xk, f.x, acc[4 * v + 0]);
            acc[4 * v + 1] = fmaf(xk, f.y, acc[4 * v + 1]);
            acc[4 * v + 2] = fmaf(xk, f.z, acc[4 * v + 2]);
            acc[4 * v + 3] = fmaf(xk, f.w, acc[4 * v + 3]);
        }
    }
    __shared__ float sred[4][D_];
    const int lane = tid & 63, wave = tid >> 6;
#pragma unroll
    for (int off = 32; off; off >>= 1)
#pragma unroll
        for (int o = 0; o < D_; ++o) acc[o] += __shfl_xor(acc[o], off, 64);
    if (lane == 0)
#pragma unroll
        for (int o = 0; o < D_; ++o) sred[wave][o] = acc[o];
    __syncthreads();
    if (tid < D_)
        z0[(size_t)b * D_ + tid] = sred[0][tid] + sred[1][tid] + sred[2][tid] + sred[3][tid];
}

// ---- root BN + tanh + head --------------------------------------------------
__global__ __launch_bounds__(256) void k_stage0b(const float* __restrict__ z0,
                                                 const float* __restrict__ g0,
                                                 const float* __restrict__ be0,
                                                 const float* __restrict__ hw0,
                                                 const float* __restrict__ hb0,
                                                 float* __restrict__ out) {
    const int tid = threadIdx.x;   // == batch row
    float acc[D_];
    const float4* zp = (const float4*)(z0 + (size_t)tid * D_);
#pragma unroll
    for (int v = 0; v < D_ / 4; ++v) {
        float4 f = zp[v];
        acc[4 * v + 0] = f.x; acc[4 * v + 1] = f.y;
        acc[4 * v + 2] = f.z; acc[4 * v + 3] = f.w;
    }
    __shared__ float sred[4][D_], qred[4][D_], Avec[D_], Cvec[D_], hwv[D_ + 1];
    const int lane = tid & 63, wave = tid >> 6;
    float s[D_], q[D_];
#pragma unroll
    for (int o = 0; o < D_; ++o) { s[o] = acc[o]; q[o] = acc[o] * acc[o]; }
#pragma unroll
    for (int off = 32; off; off >>= 1) {
#pragma unroll
        for (int o = 0; o < D_; ++o) {
            s[o] += __shfl_xor(s[o], off, 64);
            q[o] += __shfl_xor(q[o], off, 64);
        }
    }
    if (lane == 0) {
#pragma unroll
        for (int o = 0; o < D_; ++o) { sred[wave][o] = s[o]; qred[wave][o] = q[o]; }
    }
    __syncthreads();
    if (tid < D_) {
        float S = sred[0][tid] + sred[1][tid] + sred[2][tid] + sred[3][tid];
        float Q = qred[0][tid] + qred[1][tid] + qred[2][tid] + qred[3][tid];
        float mu  = S * (1.0f / B_);
        float var = fmaxf(Q * (1.0f / B_) - mu * mu, 0.0f);
        float rstd = rsqrtf(var + EPS_);
        float A = rstd * g0[tid];
        Avec[tid] = A;
        Cvec[tid] = be0[tid] - mu * A;
        hwv[tid] = hw0[tid];
    }
    if (tid == 0) hwv[D_] = hb0[0];
    __syncthreads();
    float pred = hwv[D_];
#pragma unroll
    for (int o = 0; o < D_; ++o) {
        float h = fast_tanh(fmaf(acc[o], Avec[o], Cvec[o]));
        pred = fmaf(h, hwv[o], pred);
    }
    out[tid] = pred;
}

extern "C" void kernel_launch(void* const* d_in, const int* in_sizes, int n_in,
                              void* d_out, int out_size, void* d_ws, size_t ws_size,
                              hipStream_t stream) {
    const float* genes3 = (const float*)d_in[0];
    const float* genes2 = (const float*)d_in[1];
    const float* genes1 = (const float*)d_in[2];
    const float* genes0 = (const float*)d_in[3];
    const float* W3  = (const float*)d_in[4];
    const float* g3  = (const float*)d_in[6];
    const float* be3 = (const float*)d_in[7];
    const float* W2  = (const float*)d_in[8];
    const float* g2  = (const float*)d_in[10];
    const float* be2 = (const float*)d_in[11];
    const float* W1  = (const float*)d_in[12];
    const float* g1  = (const float*)d_in[14];
    const float* be1 = (const float*)d_in[15];
    const float* W0  = (const float*)d_in[16];
    const float* g0  = (const float*)d_in[18];
    const float* be0 = (const float*)d_in[19];
    const float* hw0 = (const float*)d_in[20];
    const float* hb0 = (const float*)d_in[21];
    float* ws = (float*)d_ws;

    k_stage3<<<T3_, 256, 0, stream>>>(genes3, W3, g3, be3, ws + OFF_H3);
    k_stage_mid<T2_><<<T2_, 256, 0, stream>>>(ws + OFF_H3, genes2, W2, g2, be2, ws + OFF_H2);
    k_stage_mid<T1_><<<T1_, 256, 0, stream>>>(ws + OFF_H2, genes1, W1, g1, be1, ws + OFF_H1);
    k_stage0a<<<B_, 256, 0, stream>>>(ws + OFF_H1, genes0, W0, ws + OFF_Z0);
    k_stage0b<<<1, 256, 0, stream>>>(ws + OFF_Z0, g0, be0, hw0, hb0, (float*)d_out);
}

// Round 3
// 367.668 us; speedup vs baseline: 1.1062x; 1.1062x over previous
//
#include <hip/hip_runtime.h>
#include <hip/hip_fp16.h>

// DCell forward, MI355X (gfx950). All inputs/outputs fp32.
// One block per (term, D-chunk) => BatchNorm is block-local (stats are per
// (t,o) over the batch, independent across o => D may be split across blocks).
// Linear bias b{3,2,1,0} cancels inside BatchNorm (z - mean) => never read.
// Intermediates h3/h2 stored fp16 TERM-MAJOR [t][b][D] so that block t
// writes/reads contiguous runs (lane stride 40 B) instead of 512 KB strides.
// h1 stored fp32 BATCH-MAJOR [b][t][D] for the root GEMV's coalesced K-strided
// reads. ws: [h3 fp16 | h2 fp16 | h1 fp32 | z0 fp32] ~= 29 MB.

#define DEV static __device__ __forceinline__

constexpr int B_  = 256, G_ = 64, D_ = 20;
constexpr int T3_ = 2048, T2_ = 512, T1_ = 128;
constexpr float EPS_ = 1e-5f;
constexpr int INM = 4 * D_ + G_;   // 144

constexpr size_t N_H3 = (size_t)T3_ * B_ * D_;   // halfs
constexpr size_t N_H2 = (size_t)T2_ * B_ * D_;   // halfs
constexpr size_t N_H1 = (size_t)B_ * T1_ * D_;   // floats
constexpr size_t OFF_H3B = 0;
constexpr size_t OFF_H2B = OFF_H3B + N_H3 * 2;
constexpr size_t OFF_H1B = OFF_H2B + N_H2 * 2;
constexpr size_t OFF_Z0B = OFF_H1B + N_H1 * 4;

DEV float fast_tanh(float x) {
    // tanh(x) = 1 - 2/(exp(2x)+1); exact at +-inf, rel err ~1e-6.
    float e = __expf(2.0f * x);
    return fmaf(-2.0f, __builtin_amdgcn_rcpf(e + 1.0f), 1.0f);
}

// BN over batch (block-local: 256 threads == 256 batch rows) + tanh.
// gterm/beterm point at this term's D_ gammas/betas; o0 = D-chunk offset.
template <int N>
DEV void bn_tanh(const float (&acc)[N], const float* gterm, const float* beterm,
                 int o0, int tid, float (&h)[N]) {
    __shared__ float sred[4][N], qred[4][N], Avec[N], Cvec[N];
    const int lane = tid & 63, wave = tid >> 6;
    float s[N], q[N];
#pragma unroll
    for (int o = 0; o < N; ++o) { s[o] = acc[o]; q[o] = acc[o] * acc[o]; }
#pragma unroll
    for (int off = 32; off; off >>= 1) {
#pragma unroll
        for (int o = 0; o < N; ++o) {
            s[o] += __shfl_xor(s[o], off, 64);
            q[o] += __shfl_xor(q[o], off, 64);
        }
    }
    if (lane == 0) {
#pragma unroll
        for (int o = 0; o < N; ++o) { sred[wave][o] = s[o]; qred[wave][o] = q[o]; }
    }
    __syncthreads();
    if (tid < N) {
        float S = sred[0][tid] + sred[1][tid] + sred[2][tid] + sred[3][tid];
        float Q = qred[0][tid] + qred[1][tid] + qred[2][tid] + qred[3][tid];
        float mu  = S * (1.0f / B_);
        float var = fmaxf(Q * (1.0f / B_) - mu * mu, 0.0f);
        float rstd = rsqrtf(var + EPS_);
        float A = rstd * gterm[o0 + tid];
        Avec[tid] = A;
        Cvec[tid] = beterm[o0 + tid] - mu * A;
    }
    __syncthreads();
#pragma unroll
    for (int o = 0; o < N; ++o) h[o] = fast_tanh(fmaf(acc[o], Avec[o], Cvec[o]));
}

// ---- stratum 3 (leaves): x = genes (64 fp32), out fp16 term-major -----------
__global__ __launch_bounds__(256, 4) void k_stage3(const float* __restrict__ genes,
                                                   const float* __restrict__ W,
                                                   const float* __restrict__ g,
                                                   const float* __restrict__ be,
                                                   __half* __restrict__ hout) {
    const int t = blockIdx.x, b = threadIdx.x;
    const float4* gp = (const float4*)(genes + ((size_t)b * T3_ + t) * G_);
    float4 xv[16];                    // preload all 64 genes: 16 loads in flight
#pragma unroll
    for (int v = 0; v < 16; ++v) xv[v] = gp[v];
    const float* Wt = W + (size_t)t * (G_ * D_);
    float acc[D_] = {};
#pragma unroll
    for (int v = 0; v < 16; ++v) {
        const float xs[4] = {xv[v].x, xv[v].y, xv[v].z, xv[v].w};
#pragma unroll
        for (int j = 0; j < 4; ++j) {
            const float* w = Wt + (4 * v + j) * D_;
#pragma unroll
            for (int o = 0; o < D_; ++o) acc[o] = fmaf(xs[j], w[o], acc[o]);
        }
    }
    float h[D_];
    bn_tanh<D_>(acc, g + (size_t)t * D_, be + (size_t)t * D_, 0, b, h);
    uint2* dst = (uint2*)(hout + ((size_t)t * B_ + b) * D_);   // 40B/thread, 8-aligned
#pragma unroll
    for (int v = 0; v < 5; ++v) {
        union { __half2 h2[2]; uint2 u; } pk;
        pk.h2[0] = __floats2half2_rn(h[4 * v],     h[4 * v + 1]);
        pk.h2[1] = __floats2half2_rn(h[4 * v + 2], h[4 * v + 3]);
        dst[v] = pk.u;
    }
}

// ---- strata 2/1: x = [4 fp16 children (80) | genes (64 fp32)] ---------------
// grid = T * (D_/DCH); block handles one term's D-chunk for all 256 batch rows.
template <int T, int DCH, bool OUT_HALF_TERM_MAJOR>
__global__ __launch_bounds__(256, 4) void k_mid(const __half* __restrict__ hsrc,
                                                const float* __restrict__ genes,
                                                const float* __restrict__ W,
                                                const float* __restrict__ g,
                                                const float* __restrict__ be,
                                                void* __restrict__ hout_) {
    constexpr int NCH = D_ / DCH;
    const int t = blockIdx.x / NCH, o0 = (blockIdx.x % NCH) * DCH;
    const int b = threadIdx.x;
    const float* Wt = W + (size_t)t * (INM * D_) + o0;
    float acc[DCH] = {};
#pragma unroll
    for (int c = 0; c < 4; ++c) {     // fp16 children, term-major: contiguous
        const uint2* hp = (const uint2*)(hsrc + ((size_t)(4 * t + c) * B_ + b) * D_);
        float xc[D_];
#pragma unroll
        for (int v = 0; v < 5; ++v) {
            union { uint2 u; __half2 h2[2]; } pk;
            pk.u = hp[v];
            xc[4 * v]     = __low2float(pk.h2[0]);
            xc[4 * v + 1] = __high2float(pk.h2[0]);
            xc[4 * v + 2] = __low2float(pk.h2[1]);
            xc[4 * v + 3] = __high2float(pk.h2[1]);
        }
#pragma unroll
        for (int k = 0; k < D_; ++k) {
            const float* w = Wt + (c * D_ + k) * D_;
#pragma unroll
            for (int o = 0; o < DCH; ++o) acc[o] = fmaf(xc[k], w[o], acc[o]);
        }
    }
    const float4* gp = (const float4*)(genes + ((size_t)b * T + t) * G_);
#pragma unroll
    for (int v = 0; v < 16; ++v) {
        float4 f = gp[v];
        const float xs[4] = {f.x, f.y, f.z, f.w};
#pragma unroll
        for (int j = 0; j < 4; ++j) {
            const float* w = Wt + (4 * D_ + 4 * v + j) * D_;
#pragma unroll
            for (int o = 0; o < DCH; ++o) acc[o] = fmaf(xs[j], w[o], acc[o]);
        }
    }
    float h[DCH];
    bn_tanh<DCH>(acc, g + (size_t)t * D_, be + (size_t)t * D_, o0, b, h);
    if (OUT_HALF_TERM_MAJOR) {
        __half* hout = (__half*)hout_;
        uint* dst = (uint*)(hout + ((size_t)t * B_ + b) * D_ + o0);
#pragma unroll
        for (int v = 0; v < DCH / 2; ++v) {
            union { __half2 h2; uint u; } pk;
            pk.h2 = __floats2half2_rn(h[2 * v], h[2 * v + 1]);
            dst[v] = pk.u;
        }
    } else {
        float* dst = (float*)hout_ + ((size_t)b * T + t) * D_ + o0;
#pragma unroll
        for (int o = 0; o < DCH; ++o) dst[o] = h[o];
    }
}

// ---- root GEMV: one block per batch row, K-strided over h1 (batch-major) ----
__global__ __launch_bounds__(256, 4) void k_stage0a(const float* __restrict__ h1,
                                                    const float* __restrict__ genes0,
                                                    const float* __restrict__ W0,
                                                    float* __restrict__ z0) {
    const int b = blockIdx.x, tid = threadIdx.x;
    const float* x = h1 + (size_t)b * (T1_ * D_);
    float acc[D_] = {};
#pragma unroll
    for (int jj = 0; jj < (T1_ * D_) / 256; ++jj) {
        int k = tid + jj * 256;
        float xk = x[k];
        const float4* w = (const float4*)(W0 + (size_t)k * D_);
#pragma unroll
        for (int v = 0; v < D_ / 4; ++v) {
            float4 f = w[v];
            acc[4 * v + 0] = fmaf(xk, f.x, acc[4 * v + 0]);
            acc[4 * v + 1] = fmaf(xk, f.y, acc[4 * v + 1]);
            acc[4 * v + 2] = fmaf(xk, f.z, acc[4 * v + 2]);
            acc[4 * v + 3] = fmaf(xk, f.w, acc[4 * v + 3]);
        }
    }
    if (tid < G_) {
        float xk = genes0[(size_t)b * G_ + tid];
        const float4* w = (const float4*)(W0 + (size_t)(T1_ * D_ + tid) * D_);
#pragma unroll
        for (int v = 0; v < D_ / 4; ++v) {
            float4 f = w[v];
            acc[4 * v + 0] = fmaf(xk, f.x, acc[4 * v + 0]);
            acc[4 * v + 1] = fmaf(xk, f.y, acc[4 * v + 1]);
            acc[4 * v + 2] = fmaf(xk, f.z, acc[4 * v + 2]);
            acc[4 * v + 3] = fmaf(xk, f.w, acc[4 * v + 3]);
        }
    }
    __shared__ float sred[4][D_];
    const int lane = tid & 63, wave = tid >> 6;
#pragma unroll
    for (int off = 32; off; off >>= 1)
#pragma unroll
        for (int o = 0; o < D_; ++o) acc[o] += __shfl_xor(acc[o], off, 64);
    if (lane == 0)
#pragma unroll
        for (int o = 0; o < D_; ++o) sred[wave][o] = acc[o];
    __syncthreads();
    if (tid < D_)
        z0[(size_t)b * D_ + tid] = sred[0][tid] + sred[1][tid] + sred[2][tid] + sred[3][tid];
}

// ---- root BN + tanh + head --------------------------------------------------
__global__ __launch_bounds__(256) void k_stage0b(const float* __restrict__ z0,
                                                 const float* __restrict__ g0,
                                                 const float* __restrict__ be0,
                                                 const float* __restrict__ hw0,
                                                 const float* __restrict__ hb0,
                                                 float* __restrict__ out) {
    const int tid = threadIdx.x;   // == batch row
    float acc[D_];
    const float4* zp = (const float4*)(z0 + (size_t)tid * D_);
#pragma unroll
    for (int v = 0; v < D_ / 4; ++v) {
        float4 f = zp[v];
        acc[4 * v + 0] = f.x; acc[4 * v + 1] = f.y;
        acc[4 * v + 2] = f.z; acc[4 * v + 3] = f.w;
    }
    float h[D_];
    bn_tanh<D_>(acc, g0, be0, 0, tid, h);
    __shared__ float hwv[D_ + 1];
    if (tid < D_) hwv[tid] = hw0[tid];
    if (tid == 0) hwv[D_] = hb0[0];
    __syncthreads();
    float pred = hwv[D_];
#pragma unroll
    for (int o = 0; o < D_; ++o) pred = fmaf(h[o], hwv[o], pred);
    out[tid] = pred;
}

extern "C" void kernel_launch(void* const* d_in, const int* in_sizes, int n_in,
                              void* d_out, int out_size, void* d_ws, size_t ws_size,
                              hipStream_t stream) {
    const float* genes3 = (const float*)d_in[0];
    const float* genes2 = (const float*)d_in[1];
    const float* genes1 = (const float*)d_in[2];
    const float* genes0 = (const float*)d_in[3];
    const float* W3  = (const float*)d_in[4];
    const float* g3  = (const float*)d_in[6];
    const float* be3 = (const float*)d_in[7];
    const float* W2  = (const float*)d_in[8];
    const float* g2  = (const float*)d_in[10];
    const float* be2 = (const float*)d_in[11];
    const float* W1  = (const float*)d_in[12];
    const float* g1  = (const float*)d_in[14];
    const float* be1 = (const float*)d_in[15];
    const float* W0  = (const float*)d_in[16];
    const float* g0  = (const float*)d_in[18];
    const float* be0 = (const float*)d_in[19];
    const float* hw0 = (const float*)d_in[20];
    const float* hb0 = (const float*)d_in[21];

    char* wsb = (char*)d_ws;
    __half* h3 = (__half*)(wsb + OFF_H3B);
    __half* h2 = (__half*)(wsb + OFF_H2B);
    float*  h1 = (float*)(wsb + OFF_H1B);
    float*  z0 = (float*)(wsb + OFF_Z0B);

    k_stage3<<<T3_, 256, 0, stream>>>(genes3, W3, g3, be3, h3);
    k_mid<T2_, 10, true ><<<T2_ * 2, 256, 0, stream>>>(h3, genes2, W2, g2, be2, h2);
    k_mid<T1_, 5,  false><<<T1_ * 4, 256, 0, stream>>>(h2, genes1, W1, g1, be1, h1);
    k_stage0a<<<B_, 256, 0, stream>>>(h1, genes0, W0, z0);
    k_stage0b<<<1, 256, 0, stream>>>(z0, g0, be0, hw0, hb0, (float*)d_out);
}